// Round 4
// baseline (1496.258 us; speedup 1.0000x reference)
//
#include <hip/hip_runtime.h>
#include <math.h>

// ---------- types ----------
typedef __bf16 bf16x8 __attribute__((ext_vector_type(8)));
typedef float fx4 __attribute__((ext_vector_type(4)));
typedef unsigned short u16;
typedef unsigned short u16x8 __attribute__((ext_vector_type(8)));
typedef unsigned int u32;
typedef unsigned char u8;

__device__ __forceinline__ fx4 mfma16(bf16x8 a, bf16x8 b, fx4 c) {
  return __builtin_amdgcn_mfma_f32_16x16x32_bf16(a, b, c, 0, 0, 0);
}
__device__ __forceinline__ u16 f2bf(float f) {  // RNE float->bf16 (manual)
  u32 u = __float_as_uint(f);
  u += 0x7fffu + ((u >> 16) & 1u);
  return (u16)(u >> 16);
}
__device__ __forceinline__ u16 bfc(float f) {  // native RNE cvt (HW v_cvt)
  __bf16 h = (__bf16)f;
  return __builtin_bit_cast(u16, h);
}
__device__ __forceinline__ float ex2(float x) { return __builtin_amdgcn_exp2f(x); }

// ---------- problem constants ----------
#define BB 8
#define SS 2048   // SQ == SK
#define DD 512
#define HH 8
#define DQ 64     // QP/H
#define DV 512    // VP/H
#define VP 4096

// ---------- workspace layout (bytes) ----------
#define OFF_QP  ((size_t)0)            // 16384x512 bf16   = 16 MB
#define OFF_KP  ((size_t)16777216)     // 16384x512 bf16   = 16 MB
#define OFF_WQT ((size_t)33554432)     // 512x512 bf16
#define OFF_WKT ((size_t)34078720)     // 512x512 bf16
#define OFF_WVT ((size_t)34603008)     // 4096x512 bf16
#define OFF_WOT ((size_t)38797312)     // 512x4096 bf16
#define OFF_MB  ((size_t)42991616)     // 8*2048*2048 u8 mask = 32 MB
#define OFF_VT  ((size_t)76546048)     // 8*4096*2048 bf16 = 128 MB
#define OFF_XB  ((size_t)210763776)    // 16384x4096 bf16  = 128 MB

// ---------- weight transpose + bf16 convert: Wt[n][k] = W[k][n] ----------
__global__ __launch_bounds__(256) void transpose_w(const float* __restrict__ W,
                                                   u16* __restrict__ Wt,
                                                   int K, int N) {
  __shared__ float t[32][33];
  const int n0 = blockIdx.x * 32, k0 = blockIdx.y * 32;
  const int tx = threadIdx.x & 31, ty = threadIdx.x >> 5;
#pragma unroll
  for (int i = 0; i < 32; i += 8)
    t[ty + i][tx] = W[(size_t)(k0 + ty + i) * N + n0 + tx];
  __syncthreads();
#pragma unroll
  for (int i = 0; i < 32; i += 8)
    Wt[(size_t)(n0 + ty + i) * K + k0 + tx] = f2bf(t[tx][ty + i]);
}

// ---------- mask pack: int32 {0,1} -> u8 {0,1} ----------
__global__ __launch_bounds__(256) void mask_pack(const int* __restrict__ m,
                                                 u8* __restrict__ mb) {
  const size_t i = ((size_t)blockIdx.x * 256 + threadIdx.x) * 16;
  int4 a0 = *(const int4*)(m + i);
  int4 a1 = *(const int4*)(m + i + 4);
  int4 a2 = *(const int4*)(m + i + 8);
  int4 a3 = *(const int4*)(m + i + 12);
  uint4 o;
  o.x = (a0.x ? 1u : 0u) | ((a0.y ? 1u : 0u) << 8) | ((a0.z ? 1u : 0u) << 16) | ((a0.w ? 1u : 0u) << 24);
  o.y = (a1.x ? 1u : 0u) | ((a1.y ? 1u : 0u) << 8) | ((a1.z ? 1u : 0u) << 16) | ((a1.w ? 1u : 0u) << 24);
  o.z = (a2.x ? 1u : 0u) | ((a2.y ? 1u : 0u) << 8) | ((a2.z ? 1u : 0u) << 16) | ((a2.w ? 1u : 0u) << 24);
  o.w = (a3.x ? 1u : 0u) | ((a3.y ? 1u : 0u) << 8) | ((a3.z ? 1u : 0u) << 16) | ((a3.w ? 1u : 0u) << 24);
  *(uint4*)(mb + i) = o;
}

// ---------- GEMM: C[M,N] = A[M,K] @ Bt[N,K]^T  (m97-style 128x128 tile) ----------
template <int AFP32, int EPI>
__global__ __launch_bounds__(256) void gemm_bt(const void* __restrict__ Ap,
                                               const u16* __restrict__ Bt,
                                               void* __restrict__ Cp,
                                               int M, int N, int K,
                                               const float* __restrict__ bias,
                                               float scale) {
  __shared__ union {
    struct { u16 As[128 * 32]; u16 Bs[128 * 32]; } s;
    u16 T[4][64 * 68];  // per-wave 64(c) x 64(s) + pad4
  } sm;
  const int tid = threadIdx.x;
  const int lane = tid & 63, w = tid >> 6;
  const int lhi = lane >> 4, llo = lane & 15;
  const int wm = w >> 1, wn = w & 1;
  const int m0 = blockIdx.y * 128, n0 = blockIdx.x * 128;

  fx4 acc[4][4];
#pragma unroll
  for (int i = 0; i < 4; ++i)
#pragma unroll
    for (int j = 0; j < 4; ++j) acc[i][j] = (fx4){0.f, 0.f, 0.f, 0.f};

  for (int k0 = 0; k0 < K; k0 += 32) {
    if (AFP32) {
      const float* A = (const float*)Ap;
      const int row = tid >> 1, co = (tid & 1) * 16;
      const float* src = A + (size_t)(m0 + row) * K + k0 + co;
      float4 v0 = *(const float4*)(src + 0);
      float4 v1 = *(const float4*)(src + 4);
      float4 v2 = *(const float4*)(src + 8);
      float4 v3 = *(const float4*)(src + 12);
      u16x8 p0 = {f2bf(v0.x), f2bf(v0.y), f2bf(v0.z), f2bf(v0.w),
                  f2bf(v1.x), f2bf(v1.y), f2bf(v1.z), f2bf(v1.w)};
      u16x8 p1 = {f2bf(v2.x), f2bf(v2.y), f2bf(v2.z), f2bf(v2.w),
                  f2bf(v3.x), f2bf(v3.y), f2bf(v3.z), f2bf(v3.w)};
      *(u16x8*)&sm.s.As[row * 32 + co] = p0;
      *(u16x8*)&sm.s.As[row * 32 + co + 8] = p1;
    } else {
      const u16* A = (const u16*)Ap;
#pragma unroll
      for (int j = 0; j < 2; ++j) {
        int cc = j * 256 + tid;
        int row = cc >> 2, c8 = (cc & 3) * 8;
        *(uint4*)&sm.s.As[cc * 8] = *(const uint4*)&A[(size_t)(m0 + row) * K + k0 + c8];
      }
    }
#pragma unroll
    for (int j = 0; j < 2; ++j) {
      int cc = j * 256 + tid;
      int row = cc >> 2, c8 = (cc & 3) * 8;
      *(uint4*)&sm.s.Bs[cc * 8] = *(const uint4*)&Bt[(size_t)(n0 + row) * K + k0 + c8];
    }
    __syncthreads();
    bf16x8 af[4], bfv[4];
#pragma unroll
    for (int mi = 0; mi < 4; ++mi)
      af[mi] = *(const bf16x8*)&sm.s.As[(wm * 64 + mi * 16 + llo) * 32 + lhi * 8];
#pragma unroll
    for (int ni = 0; ni < 4; ++ni)
      bfv[ni] = *(const bf16x8*)&sm.s.Bs[(wn * 64 + ni * 16 + llo) * 32 + lhi * 8];
#pragma unroll
    for (int mi = 0; mi < 4; ++mi)
#pragma unroll
      for (int ni = 0; ni < 4; ++ni)
        acc[mi][ni] = mfma16(af[mi], bfv[ni], acc[mi][ni]);
    __syncthreads();
  }

  const int rbase = m0 + wm * 64, cbase = n0 + wn * 64;
  if (EPI == 0) {
    u16* C = (u16*)Cp;
#pragma unroll
    for (int mi = 0; mi < 4; ++mi) {
      int r0 = rbase + mi * 16 + lhi * 4;
#pragma unroll
      for (int ni = 0; ni < 4; ++ni) {
        int c = cbase + ni * 16 + llo;
#pragma unroll
        for (int r = 0; r < 4; ++r)
          C[(size_t)(r0 + r) * N + c] = f2bf(acc[mi][ni][r] * scale);
      }
    }
  } else if (EPI == 1) {
    // Vt[b][n][s]: wave-private LDS transpose, then 128B-contiguous stores.
    u16* Tw = &sm.T[w][0];
#pragma unroll
    for (int mi = 0; mi < 4; ++mi)
#pragma unroll
      for (int ni = 0; ni < 4; ++ni) {
        ushort4 pk;
        pk.x = f2bf(acc[mi][ni][0]);
        pk.y = f2bf(acc[mi][ni][1]);
        pk.z = f2bf(acc[mi][ni][2]);
        pk.w = f2bf(acc[mi][ni][3]);
        *(ushort4*)&Tw[(ni * 16 + llo) * 68 + mi * 16 + lhi * 4] = pk;
      }
    u16* VtC = (u16*)Cp;
    const int bsel = rbase >> 11;
    const int sb = rbase & 2047;
    u16* dst = VtC + ((size_t)(bsel * VP + cbase + lane)) * SS + sb;
#pragma unroll
    for (int j = 0; j < 8; ++j) {
      u16x8 vv = *(u16x8*)&Tw[lane * 68 + j * 8];
      *(u16x8*)&dst[j * 8] = vv;
    }
  } else {
    float* C = (float*)Cp;
#pragma unroll
    for (int ni = 0; ni < 4; ++ni) {
      int c = cbase + ni * 16 + llo;
      float bv = bias[c];
#pragma unroll
      for (int mi = 0; mi < 4; ++mi) {
        int r0 = rbase + mi * 16 + lhi * 4;
#pragma unroll
        for (int r = 0; r < 4; ++r)
          C[(size_t)(r0 + r) * N + c] = acc[mi][ni][r] + bv;
      }
    }
  }
}

// ---------- flash attention: swapped QK^T + fused in-register softmax ----------
// Grid 4096: xcd = lin&7 (= head h); per XCD: 16 chunks (b, dv-half) x 32
// q-tiles -> co-resident blocks share one (b,h) chunk: V 2MB + K 0.25MB in L2.
// Per 128-KV iter, wave w owns s-slice [w*32, w*32+32):
//   phase 1: S^T = mfma(K, Q) (identical fragments, swapped args) -> lane holds
//     4 CONSECUTIVE s for one q-row -> mask (4 contig bytes) + exp2 + cvt in
//     registers; P written to XOR-swizzled double-buffered Psm (ushort4).
//   barrier (one per iter; double buffer removes the second)
//   phase 2: PV exactly as before (pf b128 reads swizzle-matched).
// No Ssm, no softmax phase, no f32 roundtrip. LDS 51K->34K (3 blocks/CU).
#define KB 128
__global__ __launch_bounds__(256, 3) void attn(const u16* __restrict__ Qp,
                                               const u16* __restrict__ Kp,
                                               const u16* __restrict__ Vt,
                                               const u8* __restrict__ mb,
                                               u16* __restrict__ Xb) {
  const int lin = blockIdx.x;
  const int xcd = lin & 7, idx = lin >> 3;
  const int chunk = idx >> 5, qt = idx & 31;
  const int b = chunk >> 1, dvh = chunk & 1, h = xcd;
  const int m0 = qt * 64;
  const int tid = threadIdx.x, w = tid >> 6, lane = tid & 63;
  const int lhi = lane >> 4, llo = lane & 15;
  const int xork = (llo & 7) << 4;

  __shared__ u16 Psm[2][64 * 128];   // 2 x 16 KB, rows 256 B, XOR-swizzled
  __shared__ float sm_lw[4][64];
  __shared__ float sm_l[64];

  // Q fragments (persistent): rows m0+mt*16+llo, k = ks*32 + lhi*8
  bf16x8 qf[4][2];
#pragma unroll
  for (int mt = 0; mt < 4; ++mt)
#pragma unroll
    for (int ks = 0; ks < 2; ++ks)
      qf[mt][ks] = *(const bf16x8*)&Qp[(size_t)(b * SS + m0 + mt * 16 + llo) * 512 +
                                       h * DQ + ks * 32 + lhi * 8];

  fx4 acc[4][4];
#pragma unroll
  for (int mt = 0; mt < 4; ++mt)
#pragma unroll
    for (int nt = 0; nt < 4; ++nt) acc[mt][nt] = (fx4){0.f, 0.f, 0.f, 0.f};
  float lp[4] = {0.f, 0.f, 0.f, 0.f};

  const size_t kbase = (size_t)(b * SS) * 512 + h * DQ + lhi * 8;
  const size_t vbase =
      (size_t)(b * VP + h * DV + dvh * 256 + w * 64 + llo) * SS + lhi * 8;
  // per-q-row mask pointers (4 contiguous bytes per (mt,st) at col lhi*4)
  const u8* mrow[4];
#pragma unroll
  for (int mt = 0; mt < 4; ++mt)
    mrow[mt] = mb + (size_t)(b * SS + m0 + mt * 16 + llo) * SS + w * 32 + lhi * 4;

  for (int n0 = 0; n0 < SS; n0 += KB) {
    const int buf = (n0 >> 7) & 1;
    char* Pb = (char*)&Psm[buf][0];

    // K fragments for this wave's s-slice (identical loads to the old kf)
    bf16x8 kf[2][2];
#pragma unroll
    for (int st = 0; st < 2; ++st)
#pragma unroll
      for (int ks = 0; ks < 2; ++ks)
        kf[st][ks] = *(const bf16x8*)&Kp[kbase +
                                         (size_t)(n0 + w * 32 + st * 16 + llo) * 512 +
                                         ks * 32];
    u32 mv[4][2];
#pragma unroll
    for (int mt = 0; mt < 4; ++mt)
#pragma unroll
      for (int st = 0; st < 2; ++st)
        mv[mt][st] = *(const u32*)(mrow[mt] + n0 + st * 16);

    // ---- phase 1: S^T = K Q^T, fused masked exp2 softmax, P -> LDS ----
#pragma unroll
    for (int mt = 0; mt < 4; ++mt) {
      const int qL = mt * 16 + llo;
      char* prow = Pb + qL * 256;
#pragma unroll
      for (int st = 0; st < 2; ++st) {
        fx4 s = (fx4){0.f, 0.f, 0.f, 0.f};
        s = mfma16(kf[st][0], qf[mt][0], s);
        s = mfma16(kf[st][1], qf[mt][1], s);
        const u32 m = mv[mt][st];
        float p0 = (m & 0x000000ffu) ? ex2(s[0]) : 0.f;
        float p1 = (m & 0x0000ff00u) ? ex2(s[1]) : 0.f;
        float p2 = (m & 0x00ff0000u) ? ex2(s[2]) : 0.f;
        float p3 = (m & 0xff000000u) ? ex2(s[3]) : 0.f;
        lp[mt] += (p0 + p1) + (p2 + p3);
        ushort4 pk = {bfc(p0), bfc(p1), bfc(p2), bfc(p3)};
        *(ushort4*)(prow + ((w * 64 + st * 32 + lhi * 8) ^ xork)) = pk;
      }
    }
    __syncthreads();

    // ---- phase 2: O += P @ V (pf reads swizzle-matched, conflict-free) ----
#pragma unroll
    for (int kk = 0; kk < 4; ++kk) {
      bf16x8 pf[4];
#pragma unroll
      for (int mt = 0; mt < 4; ++mt)
        pf[mt] = *(const bf16x8*)(Pb + (mt * 16 + llo) * 256 +
                                  ((kk * 64 + lhi * 16) ^ xork));
      __builtin_amdgcn_s_setprio(1);
#pragma unroll
      for (int nt = 0; nt < 4; ++nt) {
        bf16x8 vf = *(const bf16x8*)&Vt[vbase + (size_t)(nt * 16) * SS + n0 + kk * 32];
#pragma unroll
        for (int mt = 0; mt < 4; ++mt)
          acc[mt][nt] = mfma16(pf[mt], vf, acc[mt][nt]);
      }
      __builtin_amdgcn_s_setprio(0);
    }
    // no trailing barrier: next iter writes the other Psm buffer; a wave can
    // only reach iter i+2's writes after ALL waves passed iter i+1's barrier,
    // which (program order) is after their iter-i PV reads completed.
  }

  // ---- l reduction: lanes llo/llo+16/llo+32/llo+48 share a q-row ----
#pragma unroll
  for (int mt = 0; mt < 4; ++mt) {
    lp[mt] += __shfl_xor(lp[mt], 16);
    lp[mt] += __shfl_xor(lp[mt], 32);
  }
  if (lhi == 0) {
#pragma unroll
    for (int mt = 0; mt < 4; ++mt) sm_lw[w][mt * 16 + llo] = lp[mt];
  }
  __syncthreads();
  if (tid < 64)
    sm_l[tid] = (sm_lw[0][tid] + sm_lw[1][tid]) + (sm_lw[2][tid] + sm_lw[3][tid]);
  __syncthreads();

  // ---- epilogue: normalize by l, restage through LDS, coalesced store ----
  float linv[4][4];
#pragma unroll
  for (int mt = 0; mt < 4; ++mt)
#pragma unroll
    for (int r = 0; r < 4; ++r) linv[mt][r] = 1.0f / sm_l[mt * 16 + lhi * 4 + r];

  u16* Xs = (u16*)&Psm[0][0];  // 16 rows x 264 stride u16 = 8448 B
  const int er = tid >> 4, ec = (tid & 15) * 16;
#pragma unroll
  for (int mt = 0; mt < 4; ++mt) {
#pragma unroll
    for (int nt = 0; nt < 4; ++nt)
#pragma unroll
      for (int r = 0; r < 4; ++r)
        Xs[(lhi * 4 + r) * 264 + w * 64 + nt * 16 + llo] =
            f2bf(acc[mt][nt][r] * linv[mt][r]);
    __syncthreads();
    {
      const u16* src = Xs + er * 264 + ec;
      u16* dst = Xb + (size_t)((h * 8 + b) * SS + m0 + mt * 16 + er) * 512 +
                 dvh * 256 + ec;
      uint4 a0 = *(const uint4*)(src + 0);
      uint4 a1 = *(const uint4*)(src + 8);
      *(uint4*)(dst + 0) = a0;
      *(uint4*)(dst + 8) = a1;
    }
    __syncthreads();
  }
}

// ---------- launcher ----------
extern "C" void kernel_launch(void* const* d_in, const int* in_sizes, int n_in,
                              void* d_out, int out_size, void* d_ws, size_t ws_size,
                              hipStream_t stream) {
  (void)in_sizes; (void)n_in; (void)out_size; (void)ws_size;
  const float* q_in = (const float*)d_in[0];
  const float* k_in = (const float*)d_in[1];
  const float* v_in = (const float*)d_in[2];
  const float* W_q  = (const float*)d_in[3];
  const float* W_k  = (const float*)d_in[4];
  const float* W_v  = (const float*)d_in[5];
  const float* W_o  = (const float*)d_in[6];
  const float* b_o  = (const float*)d_in[7];
  const int*   mask = (const int*)d_in[8];

  char* ws = (char*)d_ws;
  u16* Qp   = (u16*)(ws + OFF_QP);
  u16* Kp   = (u16*)(ws + OFF_KP);
  u16* Wqt  = (u16*)(ws + OFF_WQT);
  u16* Wkt  = (u16*)(ws + OFF_WKT);
  u16* Wvt  = (u16*)(ws + OFF_WVT);
  u16* Wot  = (u16*)(ws + OFF_WOT);
  u8*  Mb   = (u8*)(ws + OFF_MB);
  u16* Vt   = (u16*)(ws + OFF_VT);
  u16* Xb   = (u16*)(ws + OFF_XB);

  // weights -> transposed bf16; mask -> u8
  transpose_w<<<dim3(16, 16), 256, 0, stream>>>(W_q, Wqt, 512, 512);
  transpose_w<<<dim3(16, 16), 256, 0, stream>>>(W_k, Wkt, 512, 512);
  transpose_w<<<dim3(128, 16), 256, 0, stream>>>(W_v, Wvt, 512, 4096);
  transpose_w<<<dim3(16, 128), 256, 0, stream>>>(W_o, Wot, 4096, 512);
  mask_pack<<<dim3(8192), 256, 0, stream>>>(mask, Mb);

  // projections (Q pre-scaled by log2(e)/8 so softmax uses exp2 directly)
  gemm_bt<1, 0><<<dim3(4, 128), 256, 0, stream>>>(q_in, Wqt, Qp, 16384, 512, 512, nullptr, 0.18033688011112f);
  gemm_bt<1, 0><<<dim3(4, 128), 256, 0, stream>>>(k_in, Wkt, Kp, 16384, 512, 512, nullptr, 1.0f);
  gemm_bt<1, 1><<<dim3(32, 128), 256, 0, stream>>>(v_in, Wvt, Vt, 16384, 4096, 512, nullptr, 1.0f);

  // attention: 4096 blocks = 8 xcd(h) x 16 chunks(b,dv-half) x 32 q-tiles
  attn<<<dim3(4096), 256, 0, stream>>>(Qp, Kp, Vt, Mb, Xb);

  // output projection + bias
  gemm_bt<0, 2><<<dim3(4, 128), 256, 0, stream>>>(Xb, Wot, d_out, 16384, 512, 4096, b_o, 1.0f);
}

// Round 5
// 1319.889 us; speedup vs baseline: 1.1336x; 1.1336x over previous
//
#include <hip/hip_runtime.h>
#include <math.h>

// ---------- types ----------
typedef __bf16 bf16x8 __attribute__((ext_vector_type(8)));
typedef float fx4 __attribute__((ext_vector_type(4)));
typedef unsigned short u16;
typedef unsigned short u16x8 __attribute__((ext_vector_type(8)));
typedef unsigned int u32;
typedef unsigned char u8;

__device__ __forceinline__ fx4 mfma16(bf16x8 a, bf16x8 b, fx4 c) {
  return __builtin_amdgcn_mfma_f32_16x16x32_bf16(a, b, c, 0, 0, 0);
}
__device__ __forceinline__ u16 f2bf(float f) {  // RNE float->bf16 (manual)
  u32 u = __float_as_uint(f);
  u += 0x7fffu + ((u >> 16) & 1u);
  return (u16)(u >> 16);
}
__device__ __forceinline__ u16 bfc(float f) {  // native RNE cvt (HW v_cvt)
  __bf16 h = (__bf16)f;
  return __builtin_bit_cast(u16, h);
}
__device__ __forceinline__ float ex2(float x) { return __builtin_amdgcn_exp2f(x); }

// ---------- problem constants ----------
#define BB 8
#define SS 2048   // SQ == SK
#define DD 512
#define HH 8
#define DQ 64     // QP/H
#define DV 512    // VP/H
#define VP 4096

// ---------- workspace layout (bytes) ----------
#define OFF_QP  ((size_t)0)            // 16384x512 bf16   = 16 MB
#define OFF_KP  ((size_t)16777216)     // 16384x512 bf16   = 16 MB
#define OFF_WQT ((size_t)33554432)     // 512x512 bf16
#define OFF_WKT ((size_t)34078720)     // 512x512 bf16
#define OFF_WVT ((size_t)34603008)     // 4096x512 bf16
#define OFF_WOT ((size_t)38797312)     // 512x4096 bf16
#define OFF_MB  ((size_t)42991616)     // bit-packed mask: 8*2048*64 u32 = 4 MB
#define OFF_VT  ((size_t)76546048)     // 8*4096*2048 bf16 = 128 MB
#define OFF_XB  ((size_t)210763776)    // 16384x4096 bf16  = 128 MB

// ---------- weight transpose + bf16 convert: Wt[n][k] = W[k][n] ----------
__global__ __launch_bounds__(256) void transpose_w(const float* __restrict__ W,
                                                   u16* __restrict__ Wt,
                                                   int K, int N) {
  __shared__ float t[32][33];
  const int n0 = blockIdx.x * 32, k0 = blockIdx.y * 32;
  const int tx = threadIdx.x & 31, ty = threadIdx.x >> 5;
#pragma unroll
  for (int i = 0; i < 32; i += 8)
    t[ty + i][tx] = W[(size_t)(k0 + ty + i) * N + n0 + tx];
  __syncthreads();
#pragma unroll
  for (int i = 0; i < 32; i += 8)
    Wt[(size_t)(n0 + ty + i) * K + k0 + tx] = f2bf(t[tx][ty + i]);
}

// ---------- mask pack: 32 int32 {0,nonzero} -> 1 u32 bitfield ----------
__global__ __launch_bounds__(256) void mask_packbits(const int* __restrict__ m,
                                                     u32* __restrict__ mb) {
  const size_t widx = (size_t)blockIdx.x * 256 + threadIdx.x;  // 1M words total
  const int* src = m + widx * 32;
  u32 r = 0;
#pragma unroll
  for (int j = 0; j < 32; j += 4) {
    int4 a = *(const int4*)(src + j);
    r |= (a.x ? 1u : 0u) << j;
    r |= (a.y ? 1u : 0u) << (j + 1);
    r |= (a.z ? 1u : 0u) << (j + 2);
    r |= (a.w ? 1u : 0u) << (j + 3);
  }
  mb[widx] = r;
}

// ---------- GEMM: C[M,N] = A[M,K] @ Bt[N,K]^T  (m97-style 128x128 tile) ----------
template <int AFP32, int EPI>
__global__ __launch_bounds__(256) void gemm_bt(const void* __restrict__ Ap,
                                               const u16* __restrict__ Bt,
                                               void* __restrict__ Cp,
                                               int M, int N, int K,
                                               const float* __restrict__ bias,
                                               float scale) {
  __shared__ union {
    struct { u16 As[128 * 32]; u16 Bs[128 * 32]; } s;
    u16 T[4][64 * 68];  // per-wave 64(c) x 64(s) + pad4
  } sm;
  const int tid = threadIdx.x;
  const int lane = tid & 63, w = tid >> 6;
  const int lhi = lane >> 4, llo = lane & 15;
  const int wm = w >> 1, wn = w & 1;
  const int m0 = blockIdx.y * 128, n0 = blockIdx.x * 128;

  fx4 acc[4][4];
#pragma unroll
  for (int i = 0; i < 4; ++i)
#pragma unroll
    for (int j = 0; j < 4; ++j) acc[i][j] = (fx4){0.f, 0.f, 0.f, 0.f};

  for (int k0 = 0; k0 < K; k0 += 32) {
    if (AFP32) {
      const float* A = (const float*)Ap;
      const int row = tid >> 1, co = (tid & 1) * 16;
      const float* src = A + (size_t)(m0 + row) * K + k0 + co;
      float4 v0 = *(const float4*)(src + 0);
      float4 v1 = *(const float4*)(src + 4);
      float4 v2 = *(const float4*)(src + 8);
      float4 v3 = *(const float4*)(src + 12);
      u16x8 p0 = {f2bf(v0.x), f2bf(v0.y), f2bf(v0.z), f2bf(v0.w),
                  f2bf(v1.x), f2bf(v1.y), f2bf(v1.z), f2bf(v1.w)};
      u16x8 p1 = {f2bf(v2.x), f2bf(v2.y), f2bf(v2.z), f2bf(v2.w),
                  f2bf(v3.x), f2bf(v3.y), f2bf(v3.z), f2bf(v3.w)};
      *(u16x8*)&sm.s.As[row * 32 + co] = p0;
      *(u16x8*)&sm.s.As[row * 32 + co + 8] = p1;
    } else {
      const u16* A = (const u16*)Ap;
#pragma unroll
      for (int j = 0; j < 2; ++j) {
        int cc = j * 256 + tid;
        int row = cc >> 2, c8 = (cc & 3) * 8;
        *(uint4*)&sm.s.As[cc * 8] = *(const uint4*)&A[(size_t)(m0 + row) * K + k0 + c8];
      }
    }
#pragma unroll
    for (int j = 0; j < 2; ++j) {
      int cc = j * 256 + tid;
      int row = cc >> 2, c8 = (cc & 3) * 8;
      *(uint4*)&sm.s.Bs[cc * 8] = *(const uint4*)&Bt[(size_t)(n0 + row) * K + k0 + c8];
    }
    __syncthreads();
    bf16x8 af[4], bfv[4];
#pragma unroll
    for (int mi = 0; mi < 4; ++mi)
      af[mi] = *(const bf16x8*)&sm.s.As[(wm * 64 + mi * 16 + llo) * 32 + lhi * 8];
#pragma unroll
    for (int ni = 0; ni < 4; ++ni)
      bfv[ni] = *(const bf16x8*)&sm.s.Bs[(wn * 64 + ni * 16 + llo) * 32 + lhi * 8];
#pragma unroll
    for (int mi = 0; mi < 4; ++mi)
#pragma unroll
      for (int ni = 0; ni < 4; ++ni)
        acc[mi][ni] = mfma16(af[mi], bfv[ni], acc[mi][ni]);
    __syncthreads();
  }

  const int rbase = m0 + wm * 64, cbase = n0 + wn * 64;
  if (EPI == 0) {
    u16* C = (u16*)Cp;
#pragma unroll
    for (int mi = 0; mi < 4; ++mi) {
      int r0 = rbase + mi * 16 + lhi * 4;
#pragma unroll
      for (int ni = 0; ni < 4; ++ni) {
        int c = cbase + ni * 16 + llo;
#pragma unroll
        for (int r = 0; r < 4; ++r)
          C[(size_t)(r0 + r) * N + c] = f2bf(acc[mi][ni][r] * scale);
      }
    }
  } else if (EPI == 1) {
    // Vt[b][n][s]: wave-private LDS transpose, then 128B-contiguous stores.
    u16* Tw = &sm.T[w][0];
#pragma unroll
    for (int mi = 0; mi < 4; ++mi)
#pragma unroll
      for (int ni = 0; ni < 4; ++ni) {
        ushort4 pk;
        pk.x = f2bf(acc[mi][ni][0]);
        pk.y = f2bf(acc[mi][ni][1]);
        pk.z = f2bf(acc[mi][ni][2]);
        pk.w = f2bf(acc[mi][ni][3]);
        *(ushort4*)&Tw[(ni * 16 + llo) * 68 + mi * 16 + lhi * 4] = pk;
      }
    u16* VtC = (u16*)Cp;
    const int bsel = rbase >> 11;
    const int sb = rbase & 2047;
    u16* dst = VtC + ((size_t)(bsel * VP + cbase + lane)) * SS + sb;
#pragma unroll
    for (int j = 0; j < 8; ++j) {
      u16x8 vv = *(u16x8*)&Tw[lane * 68 + j * 8];
      *(u16x8*)&dst[j * 8] = vv;
    }
  } else {
    float* C = (float*)Cp;
#pragma unroll
    for (int ni = 0; ni < 4; ++ni) {
      int c = cbase + ni * 16 + llo;
      float bv = bias[c];
#pragma unroll
      for (int mi = 0; mi < 4; ++mi) {
        int r0 = rbase + mi * 16 + lhi * 4;
#pragma unroll
        for (int r = 0; r < 4; ++r)
          C[(size_t)(r0 + r) * N + c] = acc[mi][ni][r] + bv;
      }
    }
  }
}

// ---------- flash attention: pipelined swapped-QK^T + in-register softmax ----
// Grid 4096: xcd = lin&7 (= head h); per XCD 16 chunks (b, dv-half) x 32
// q-tiles -> chunk working set (V 1MB + K 0.25MB + bitmask 0.5MB) < 4MB L2.
// Pipeline (raw barrier keeps vmcnt outstanding; no __syncthreads drain):
//   phase1(i): QK(kf=K(i)) -> masked exp2 in regs -> P ushort4 -> Psm[buf]
//   lgkmcnt(0); s_barrier; sched_barrier
//   issue kf=K(i+1), mvc=mask(i+1)      (covered by phase 2)
//   phase2(i): pf ds_read + PV with vf=V(i)
//   issue vf=V(i+1)                      (covered by next phase 1)
// P layout Psm[2][4][64][40] u16: 80B rows, write/read <=2-way bank aliasing.
#define KB 128
__global__ __launch_bounds__(256, 2) void attn(const u16* __restrict__ Qp,
                                               const u16* __restrict__ Kp,
                                               const u16* __restrict__ Vt,
                                               const u32* __restrict__ mb,
                                               u16* __restrict__ Xb) {
  const int lin = blockIdx.x;
  const int xcd = lin & 7, idx = lin >> 3;
  const int chunk = idx >> 5, qt = idx & 31;
  const int b = chunk >> 1, dvh = chunk & 1, h = xcd;
  const int m0 = qt * 64;
  const int tid = threadIdx.x, w = tid >> 6, lane = tid & 63;
  const int lhi = lane >> 4, llo = lane & 15;

  __shared__ u16 Psm[2][4][64][40];   // 40960 B
  __shared__ float sm_lw[4][64];
  __shared__ float sm_l[64];

  // Q fragments (persistent): rows m0+mt*16+llo, k = ks*32 + lhi*8
  bf16x8 qf[4][2];
#pragma unroll
  for (int mt = 0; mt < 4; ++mt)
#pragma unroll
    for (int ks = 0; ks < 2; ++ks)
      qf[mt][ks] = *(const bf16x8*)&Qp[(size_t)(b * SS + m0 + mt * 16 + llo) * 512 +
                                       h * DQ + ks * 32 + lhi * 8];

  fx4 acc[4][4];
#pragma unroll
  for (int mt = 0; mt < 4; ++mt)
#pragma unroll
    for (int nt = 0; nt < 4; ++nt) acc[mt][nt] = (fx4){0.f, 0.f, 0.f, 0.f};
  float lp[4] = {0.f, 0.f, 0.f, 0.f};

  const size_t kbase = (size_t)(b * SS) * 512 + h * DQ + lhi * 8;
  const size_t vbase =
      (size_t)(b * VP + h * DV + dvh * 256 + w * 64 + llo) * SS + lhi * 8;
  // bit-mask: word (n0/32 + w) of row q covers this wave's 32-s slice
  const u32* mrowp[4];
#pragma unroll
  for (int mt = 0; mt < 4; ++mt)
    mrowp[mt] = mb + (size_t)(b * SS + m0 + mt * 16 + llo) * 64 + w;
  const u32 bm0 = 1u << (lhi * 4), bm1 = bm0 << 1, bm2 = bm0 << 2, bm3 = bm0 << 3;

  // ---- prologue: issue iter-0 loads (K, mask, V) ----
  bf16x8 kf[2][2];
  u32 mvc[4];
  bf16x8 vf[4][4];
#pragma unroll
  for (int st = 0; st < 2; ++st)
#pragma unroll
    for (int ks = 0; ks < 2; ++ks)
      kf[st][ks] = *(const bf16x8*)&Kp[kbase +
                                       (size_t)(w * 32 + st * 16 + llo) * 512 +
                                       ks * 32];
#pragma unroll
  for (int mt = 0; mt < 4; ++mt) mvc[mt] = mrowp[mt][0];
#pragma unroll
  for (int kk = 0; kk < 4; ++kk)
#pragma unroll
    for (int nt = 0; nt < 4; ++nt)
      vf[kk][nt] = *(const bf16x8*)&Vt[vbase + (size_t)(nt * 16) * SS + kk * 32];

  for (int n0 = 0; n0 < SS; n0 += KB) {
    const int buf = (n0 >> 7) & 1;
    const int nn = (n0 + KB) & (SS - 1);  // wrapped prefetch index (last iter: dummy)

    // ---- phase 1: S^T = K Q^T, masked exp2 softmax in regs, P -> LDS ----
#pragma unroll
    for (int mt = 0; mt < 4; ++mt) {
      const int qL = mt * 16 + llo;
      u16* Pw = &Psm[buf][w][qL][0];
#pragma unroll
      for (int st = 0; st < 2; ++st) {
        fx4 s = (fx4){0.f, 0.f, 0.f, 0.f};
        s = mfma16(kf[st][0], qf[mt][0], s);
        s = mfma16(kf[st][1], qf[mt][1], s);
        const u32 mst = mvc[mt] >> (st * 16);
        float p0 = (mst & bm0) ? ex2(s[0]) : 0.f;
        float p1 = (mst & bm1) ? ex2(s[1]) : 0.f;
        float p2 = (mst & bm2) ? ex2(s[2]) : 0.f;
        float p3 = (mst & bm3) ? ex2(s[3]) : 0.f;
        lp[mt] += (p0 + p1) + (p2 + p3);
        ushort4 pk = {bfc(p0), bfc(p1), bfc(p2), bfc(p3)};
        *(ushort4*)&Pw[st * 16 + lhi * 4] = pk;
      }
    }

    // ---- raw barrier: LDS visibility only, global loads stay in flight ----
    asm volatile("s_waitcnt lgkmcnt(0)" ::: "memory");
    __builtin_amdgcn_s_barrier();
    __builtin_amdgcn_sched_barrier(0);

    // ---- issue K/mask for next iter (latency covered by phase 2) ----
#pragma unroll
    for (int st = 0; st < 2; ++st)
#pragma unroll
      for (int ks = 0; ks < 2; ++ks)
        kf[st][ks] = *(const bf16x8*)&Kp[kbase +
                                         (size_t)(nn + w * 32 + st * 16 + llo) * 512 +
                                         ks * 32];
#pragma unroll
    for (int mt = 0; mt < 4; ++mt) mvc[mt] = mrowp[mt][nn >> 5];

    // ---- phase 2: O += P @ V ----
    const u16* Pb = &Psm[buf][0][0][0];
#pragma unroll
    for (int kk = 0; kk < 4; ++kk) {
      bf16x8 pf[4];
#pragma unroll
      for (int mt = 0; mt < 4; ++mt)
        pf[mt] = *(const bf16x8*)&Pb[(size_t)(kk * 64 + mt * 16 + llo) * 40 + lhi * 8];
      __builtin_amdgcn_s_setprio(1);
#pragma unroll
      for (int nt = 0; nt < 4; ++nt)
#pragma unroll
        for (int mt = 0; mt < 4; ++mt)
          acc[mt][nt] = mfma16(pf[mt], vf[kk][nt], acc[mt][nt]);
      __builtin_amdgcn_s_setprio(0);
    }

    // ---- issue V for next iter (latency covered by next phase 1) ----
#pragma unroll
    for (int kk = 0; kk < 4; ++kk)
#pragma unroll
      for (int nt = 0; nt < 4; ++nt)
        vf[kk][nt] = *(const bf16x8*)&Vt[vbase + (size_t)(nt * 16) * SS + nn + kk * 32];
    // no trailing barrier: next phase 1 writes the other Psm buffer; barrier
    // i+1 separates all waves' phase-2(i) reads from phase-1(i+2) writes.
  }

  // ---- l reduction: lanes llo/llo+16/llo+32/llo+48 share a q-row ----
#pragma unroll
  for (int mt = 0; mt < 4; ++mt) {
    lp[mt] += __shfl_xor(lp[mt], 16);
    lp[mt] += __shfl_xor(lp[mt], 32);
  }
  if (lhi == 0) {
#pragma unroll
    for (int mt = 0; mt < 4; ++mt) sm_lw[w][mt * 16 + llo] = lp[mt];
  }
  __syncthreads();
  if (tid < 64)
    sm_l[tid] = (sm_lw[0][tid] + sm_lw[1][tid]) + (sm_lw[2][tid] + sm_lw[3][tid]);
  __syncthreads();

  // ---- epilogue: normalize by l, restage through LDS, coalesced store ----
  float linv[4][4];
#pragma unroll
  for (int mt = 0; mt < 4; ++mt)
#pragma unroll
    for (int r = 0; r < 4; ++r) linv[mt][r] = 1.0f / sm_l[mt * 16 + lhi * 4 + r];

  u16* Xs = &Psm[0][0][0][0];  // 16 rows x 264 u16 stride = 8448 B
  const int er = tid >> 4, ec = (tid & 15) * 16;
#pragma unroll
  for (int mt = 0; mt < 4; ++mt) {
#pragma unroll
    for (int nt = 0; nt < 4; ++nt)
#pragma unroll
      for (int r = 0; r < 4; ++r)
        Xs[(lhi * 4 + r) * 264 + w * 64 + nt * 16 + llo] =
            f2bf(acc[mt][nt][r] * linv[mt][r]);
    __syncthreads();
    {
      const u16* src = Xs + er * 264 + ec;
      u16* dst = Xb + (size_t)((h * 8 + b) * SS + m0 + mt * 16 + er) * 512 +
                 dvh * 256 + ec;
      uint4 a0 = *(const uint4*)(src + 0);
      uint4 a1 = *(const uint4*)(src + 8);
      *(uint4*)(dst + 0) = a0;
      *(uint4*)(dst + 8) = a1;
    }
    __syncthreads();
  }
}

// ---------- launcher ----------
extern "C" void kernel_launch(void* const* d_in, const int* in_sizes, int n_in,
                              void* d_out, int out_size, void* d_ws, size_t ws_size,
                              hipStream_t stream) {
  (void)in_sizes; (void)n_in; (void)out_size; (void)ws_size;
  const float* q_in = (const float*)d_in[0];
  const float* k_in = (const float*)d_in[1];
  const float* v_in = (const float*)d_in[2];
  const float* W_q  = (const float*)d_in[3];
  const float* W_k  = (const float*)d_in[4];
  const float* W_v  = (const float*)d_in[5];
  const float* W_o  = (const float*)d_in[6];
  const float* b_o  = (const float*)d_in[7];
  const int*   mask = (const int*)d_in[8];

  char* ws = (char*)d_ws;
  u16* Qp   = (u16*)(ws + OFF_QP);
  u16* Kp   = (u16*)(ws + OFF_KP);
  u16* Wqt  = (u16*)(ws + OFF_WQT);
  u16* Wkt  = (u16*)(ws + OFF_WKT);
  u16* Wvt  = (u16*)(ws + OFF_WVT);
  u16* Wot  = (u16*)(ws + OFF_WOT);
  u32* Mb   = (u32*)(ws + OFF_MB);
  u16* Vt   = (u16*)(ws + OFF_VT);
  u16* Xb   = (u16*)(ws + OFF_XB);

  // weights -> transposed bf16; mask -> bitfield (32 MB -> 4 MB)
  transpose_w<<<dim3(16, 16), 256, 0, stream>>>(W_q, Wqt, 512, 512);
  transpose_w<<<dim3(16, 16), 256, 0, stream>>>(W_k, Wkt, 512, 512);
  transpose_w<<<dim3(128, 16), 256, 0, stream>>>(W_v, Wvt, 512, 4096);
  transpose_w<<<dim3(16, 128), 256, 0, stream>>>(W_o, Wot, 4096, 512);
  mask_packbits<<<dim3(4096), 256, 0, stream>>>(mask, Mb);

  // projections (Q pre-scaled by log2(e)/8 so softmax uses exp2 directly)
  gemm_bt<1, 0><<<dim3(4, 128), 256, 0, stream>>>(q_in, Wqt, Qp, 16384, 512, 512, nullptr, 0.18033688011112f);
  gemm_bt<1, 0><<<dim3(4, 128), 256, 0, stream>>>(k_in, Wkt, Kp, 16384, 512, 512, nullptr, 1.0f);
  gemm_bt<1, 1><<<dim3(32, 128), 256, 0, stream>>>(v_in, Wvt, Vt, 16384, 4096, 512, nullptr, 1.0f);

  // attention: 4096 blocks = 8 xcd(h) x 16 chunks(b,dv-half) x 32 q-tiles
  attn<<<dim3(4096), 256, 0, stream>>>(Qp, Kp, Vt, Mb, Xb);

  // output projection + bias
  gemm_bt<0, 2><<<dim3(4, 128), 256, 0, stream>>>(Xb, Wot, d_out, 16384, 512, 4096, b_o, 1.0f);
}